// Round 2
// baseline (311.886 us; speedup 1.0000x reference)
//
#include <hip/hip_runtime.h>
#include <hip/hip_bf16.h>
#include <cstdint>
#include <cstddef>

// Problem constants
#define B_N 8192
#define D_K 1024
#define H_N 400
#define HP  416          // H padded to multiple of 32 for GEMM2 K-loop
#define K2_N 512
#define E_N 16
#define L_N 256
#define TM 64
#define PAD_ROWS (B_N + E_N * TM)   // 9216
#define NTILES (PAD_ROWS / TM)      // 144

typedef short bf16x8 __attribute__((ext_vector_type(8)));
typedef float f32x4 __attribute__((ext_vector_type(4)));

static __device__ __forceinline__ unsigned short f2bf(float f) {
  union { float f; unsigned int u; } c; c.f = f;
  unsigned int u = c.u + 0x7fffu + ((c.u >> 16) & 1u);  // RNE
  return (unsigned short)(u >> 16);
}
static __device__ __forceinline__ unsigned int pkbf(float a, float b) {
  union { __hip_bfloat162 v; unsigned int u; } c;
  c.v = __float22bfloat162_rn(make_float2(a, b));
  return c.u;
}

// ---------------- grouping: hist -> offsets -> scatter ----------------
__global__ __launch_bounds__(256) void hist_kernel(const int* __restrict__ idx,
                                                   int* __restrict__ hist) {
  __shared__ int h[E_N];
  int t = threadIdx.x;
  if (t < E_N) h[t] = 0;
  __syncthreads();
  int b = blockIdx.x * 256 + t;   // grid 32 x 256 = 8192 exact
  atomicAdd(&h[idx[b]], 1);
  __syncthreads();
  if (t < E_N) hist[blockIdx.x * E_N + t] = h[t];
}

__global__ __launch_bounds__(256) void offs_kernel(const int* __restrict__ hist,
                                                   int* __restrict__ off_al,
                                                   int* __restrict__ cur,
                                                   int* __restrict__ order) {
  __shared__ int cnt[E_N];
  int t = threadIdx.x;
  if (t < E_N) {
    int s = 0;
    for (int b = 0; b < 32; ++b) s += hist[b * E_N + t];
    cnt[t] = s;
  }
  __syncthreads();
  if (t == 0) {
    int acc = 0;
    for (int e = 0; e < E_N; ++e) {
      off_al[e] = acc;
      cur[e] = acc;
      acc += ((cnt[e] + TM - 1) / TM) * TM;
    }
    off_al[E_N] = acc;
  }
  for (int i = t; i < PAD_ROWS; i += 256) order[i] = -1;
}

__global__ __launch_bounds__(256) void scatter_kernel(const int* __restrict__ idx,
                                                      int* __restrict__ cur,
                                                      int* __restrict__ order) {
  int b = blockIdx.x * 256 + threadIdx.x;
  int e = idx[b];
  int p = atomicAdd(&cur[e], 1);
  order[p] = b;
}

// ---------------- prep: transpose + cvt W [K][N] f32 -> [N][Kd] bf16 ----------------
// grid: (ceil(Kd/64), ceil(N/64), E)
__global__ __launch_bounds__(256) void transpose_kernel(const float* __restrict__ src,
                                                        unsigned short* __restrict__ dst,
                                                        int K, int N, int Kd) {
  __shared__ unsigned short Ls[64][72];
  const int e  = blockIdx.z;
  const int k0 = blockIdx.x * 64;
  const int n0 = blockIdx.y * 64;
  const float* S = src + (size_t)e * K * N;
  unsigned short* Dt = dst + (size_t)e * N * Kd;
  const int t = threadIdx.x;
  const int kk = t >> 4;          // 0..15
  const int nn = (t & 15) * 4;    // 0..60
#pragma unroll
  for (int p = 0; p < 4; ++p) {
    int k = k0 + p * 16 + kk;
    int n = n0 + nn;
    float4 v = make_float4(0.f, 0.f, 0.f, 0.f);
    if (k < K && n + 3 < N) v = *(const float4*)(S + (size_t)k * N + n);
    Ls[nn + 0][p * 16 + kk] = f2bf(v.x);
    Ls[nn + 1][p * 16 + kk] = f2bf(v.y);
    Ls[nn + 2][p * 16 + kk] = f2bf(v.z);
    Ls[nn + 3][p * 16 + kk] = f2bf(v.w);
  }
  __syncthreads();
  const int n2 = t >> 3;   // 0..31
  const int ch = t & 7;    // 0..7 (8 bf16 = 16B each)
#pragma unroll
  for (int p = 0; p < 2; ++p) {
    int n = n0 + p * 32 + n2;
    int k = k0 + ch * 8;
    if (n < N && k < Kd)
      *(uint4*)(Dt + (size_t)n * Kd + k) = *(const uint4*)&Ls[p * 32 + n2][ch * 8];
  }
}

// ---------------- GEMM1: h1 = relu(Xg @ W1[e] + b1[e]) (bf16 MFMA) ----------------
// BM=64, BN=400 (25 n-tiles), BK=32. 4 waves, wave w takes n-tiles {w, w+4, ...}.
__global__ __launch_bounds__(256) void gemm1_kernel(const float* __restrict__ x,
                                                    const unsigned short* __restrict__ Wt1,
                                                    const float* __restrict__ b1,
                                                    const int* __restrict__ off_al,
                                                    const int* __restrict__ order,
                                                    unsigned short* __restrict__ h1buf) {
  __shared__ int offs[E_N + 1];
  __shared__ int rowidx[TM];
  __shared__ unsigned short As[64 * 40];   // [m][k], stride 40 bf16 (80B) pad
  __shared__ unsigned short Bs[400 * 40];  // [n][k]
  const int tid = threadIdx.x;
  const int m0 = blockIdx.x * TM;
  if (tid <= E_N) offs[tid] = off_al[tid];
  if (tid < TM) rowidx[tid] = order[m0 + tid];
  __syncthreads();
  const int total = offs[E_N];
  if (m0 >= total) return;
  int e = 0;
  while (m0 >= offs[e + 1]) ++e;

  const int arow = tid >> 2;            // 0..63
  const int akq  = (tid & 3) * 8;       // 0,8,16,24
  const long asrc = rowidx[arow];
  const unsigned short* Wt1e = Wt1 + (size_t)e * H_N * D_K;

  const int lane = tid & 63, w = tid >> 6;
  const int ln = lane & 15, q = lane >> 4;

  f32x4 acc[4][7] = {};

  // prefetch k=0
  float4 aA = make_float4(0, 0, 0, 0), aB = aA;
  if (asrc >= 0) {
    aA = *(const float4*)(x + (size_t)asrc * D_K + 0 + akq);
    aB = *(const float4*)(x + (size_t)asrc * D_K + 0 + akq + 4);
  }
  uint4 breg[7];
#pragma unroll
  for (int j = 0; j < 7; ++j) {
    int i = tid + 256 * j;
    if (i < H_N * 4)
      breg[j] = *(const uint4*)(Wt1e + (size_t)(i >> 2) * D_K + 0 + (i & 3) * 8);
  }

  for (int k0 = 0; k0 < D_K; k0 += 32) {
    // commit staged regs -> LDS
    uint4 aw;
    aw.x = pkbf(aA.x, aA.y); aw.y = pkbf(aA.z, aA.w);
    aw.z = pkbf(aB.x, aB.y); aw.w = pkbf(aB.z, aB.w);
    *(uint4*)&As[arow * 40 + akq] = aw;
#pragma unroll
    for (int j = 0; j < 7; ++j) {
      int i = tid + 256 * j;
      if (i < H_N * 4) *(uint4*)&Bs[(i >> 2) * 40 + (i & 3) * 8] = breg[j];
    }
    __syncthreads();

    // prefetch next k-step (overlaps MFMAs below)
    int kn = k0 + 32;
    if (kn < D_K) {
      if (asrc >= 0) {
        aA = *(const float4*)(x + (size_t)asrc * D_K + kn + akq);
        aB = *(const float4*)(x + (size_t)asrc * D_K + kn + akq + 4);
      }
#pragma unroll
      for (int j = 0; j < 7; ++j) {
        int i = tid + 256 * j;
        if (i < H_N * 4)
          breg[j] = *(const uint4*)(Wt1e + (size_t)(i >> 2) * D_K + kn + (i & 3) * 8);
      }
    }

    bf16x8 af[4];
#pragma unroll
    for (int i = 0; i < 4; ++i)
      af[i] = *(const bf16x8*)&As[(16 * i + ln) * 40 + 8 * q];
#pragma unroll
    for (int t = 0; t < 7; ++t) {
      int T = w + 4 * t;
      if (T < 25) {
        bf16x8 bf = *(const bf16x8*)&Bs[(16 * T + ln) * 40 + 8 * q];
#pragma unroll
        for (int i = 0; i < 4; ++i)
          acc[i][t] = __builtin_amdgcn_mfma_f32_16x16x32_bf16(af[i], bf, acc[i][t], 0, 0, 0);
      }
    }
    __syncthreads();
  }

  // epilogue: bias + relu + bf16 store (permuted rows, [m][HP])
#pragma unroll
  for (int t = 0; t < 7; ++t) {
    int T = w + 4 * t;
    if (T < 25) {
      int n = 16 * T + ln;
      float bias = b1[e * H_N + n];
#pragma unroll
      for (int i = 0; i < 4; ++i) {
#pragma unroll
        for (int r = 0; r < 4; ++r) {
          int m = m0 + 16 * i + 4 * q + r;
          float v = acc[i][t][r] + bias;
          h1buf[(size_t)m * HP + n] = f2bf(fmaxf(v, 0.f));
        }
      }
    }
  }
  // zero K-pad cols [400,416)
  if (tid < TM) {
    uint4 z = make_uint4(0, 0, 0, 0);
    *(uint4*)&h1buf[(size_t)(m0 + tid) * HP + 400] = z;
    *(uint4*)&h1buf[(size_t)(m0 + tid) * HP + 408] = z;
  }
}

// ---------------- GEMM2: out = h1 @ W2[e] + b2[e], scatter ----------------
// BM=64, BN=512 (32 n-tiles), BK=32, K=416 (13 steps).
__global__ __launch_bounds__(256) void gemm2_kernel(const unsigned short* __restrict__ h1buf,
                                                    const unsigned short* __restrict__ Wt2,
                                                    const float* __restrict__ b2,
                                                    const int* __restrict__ off_al,
                                                    const int* __restrict__ order,
                                                    float* __restrict__ out) {
  __shared__ int offs[E_N + 1];
  __shared__ int rowidx[TM];
  __shared__ unsigned short As[64 * 40];
  __shared__ unsigned short Bs[512 * 40];
  const int tid = threadIdx.x;
  const int m0 = blockIdx.x * TM;
  if (tid <= E_N) offs[tid] = off_al[tid];
  if (tid < TM) rowidx[tid] = order[m0 + tid];
  __syncthreads();
  const int total = offs[E_N];
  if (m0 >= total) return;
  int e = 0;
  while (m0 >= offs[e + 1]) ++e;

  const int arow = tid >> 2, ach = tid & 3;
  const unsigned short* Wt2e = Wt2 + (size_t)e * K2_N * HP;

  const int lane = tid & 63, w = tid >> 6;
  const int ln = lane & 15, q = lane >> 4;

  f32x4 acc[4][8] = {};

  uint4 areg = *(const uint4*)(h1buf + (size_t)(m0 + arow) * HP + 0 + ach * 8);
  uint4 breg[8];
#pragma unroll
  for (int j = 0; j < 8; ++j) {
    int i = tid + 256 * j;
    breg[j] = *(const uint4*)(Wt2e + (size_t)(i >> 2) * HP + 0 + (i & 3) * 8);
  }

  for (int k0 = 0; k0 < HP; k0 += 32) {
    *(uint4*)&As[arow * 40 + ach * 8] = areg;
#pragma unroll
    for (int j = 0; j < 8; ++j) {
      int i = tid + 256 * j;
      *(uint4*)&Bs[(i >> 2) * 40 + (i & 3) * 8] = breg[j];
    }
    __syncthreads();

    int kn = k0 + 32;
    if (kn < HP) {
      areg = *(const uint4*)(h1buf + (size_t)(m0 + arow) * HP + kn + ach * 8);
#pragma unroll
      for (int j = 0; j < 8; ++j) {
        int i = tid + 256 * j;
        breg[j] = *(const uint4*)(Wt2e + (size_t)(i >> 2) * HP + kn + (i & 3) * 8);
      }
    }

    bf16x8 af[4];
#pragma unroll
    for (int i = 0; i < 4; ++i)
      af[i] = *(const bf16x8*)&As[(16 * i + ln) * 40 + 8 * q];
#pragma unroll
    for (int t = 0; t < 8; ++t) {
      int T = w + 4 * t;
      bf16x8 bf = *(const bf16x8*)&Bs[(16 * T + ln) * 40 + 8 * q];
#pragma unroll
      for (int i = 0; i < 4; ++i)
        acc[i][t] = __builtin_amdgcn_mfma_f32_16x16x32_bf16(af[i], bf, acc[i][t], 0, 0, 0);
    }
    __syncthreads();
  }

#pragma unroll
  for (int t = 0; t < 8; ++t) {
    int T = w + 4 * t;
    int n = 16 * T + ln;
    float bias = b2[e * K2_N + n];
#pragma unroll
    for (int i = 0; i < 4; ++i) {
#pragma unroll
      for (int r = 0; r < 4; ++r) {
        int s = rowidx[16 * i + 4 * q + r];
        if (s >= 0) {
          float v = acc[i][t][r] + bias;
          if (n < L_N) out[(size_t)s * L_N + n] = v;
          else         out[(size_t)(B_N + s) * L_N + (n - L_N)] = v;
        }
      }
    }
  }
}

extern "C" void kernel_launch(void* const* d_in, const int* in_sizes, int n_in,
                              void* d_out, int out_size, void* d_ws, size_t ws_size,
                              hipStream_t stream) {
  const float* x   = (const float*)d_in[0];
  const int*   idx = (const int*)d_in[1];
  const float* W1  = (const float*)d_in[2];
  const float* b1  = (const float*)d_in[3];
  const float* W2  = (const float*)d_in[4];
  const float* b2  = (const float*)d_in[5];
  float* out = (float*)d_out;

  // ws layout (bytes):
  // off_al @0 (128) | cur @128 (64) | hist @192 (2048) | order @2240 (36864)
  // h1buf @39104 (9216*416*2 = 7667712) | Wt1 @7706816 (13107200) | Wt2 ...
  char* ws = (char*)d_ws;
  int* off_al = (int*)(ws + 0);
  int* cur    = (int*)(ws + 128);
  int* hist   = (int*)(ws + 192);
  int* order  = (int*)(ws + 2240);
  unsigned short* h1buf = (unsigned short*)(ws + 39104);
  unsigned short* Wt1   = (unsigned short*)(ws + 7706816);
  const size_t WT1_BYTES = (size_t)E_N * H_N * D_K * 2;    // 13107200
  const size_t WT2_BYTES = (size_t)E_N * K2_N * HP * 2;    // 6815744
  const size_t FLAT_END = 7706816 + WT1_BYTES + WT2_BYTES; // ~26.4 MB
  const bool flat = ws_size >= FLAT_END;
  unsigned short* Wt2 = flat ? (unsigned short*)(ws + 7706816 + WT1_BYTES)
                             : Wt1;  // overlap: W2 transposed after gemm1

  hist_kernel<<<32, 256, 0, stream>>>(idx, hist);
  offs_kernel<<<1, 256, 0, stream>>>(hist, off_al, cur, order);
  scatter_kernel<<<32, 256, 0, stream>>>(idx, cur, order);
  transpose_kernel<<<dim3(D_K / 64, 7, E_N), 256, 0, stream>>>(W1, Wt1, D_K, H_N, D_K);
  if (flat)
    transpose_kernel<<<dim3(HP / 64 + 1, K2_N / 64, E_N), 256, 0, stream>>>(W2, Wt2, H_N, K2_N, HP);
  gemm1_kernel<<<NTILES, 256, 0, stream>>>(x, Wt1, b1, off_al, order, h1buf);
  if (!flat)
    transpose_kernel<<<dim3(HP / 64 + 1, K2_N / 64, E_N), 256, 0, stream>>>(W2, Wt2, H_N, K2_N, HP);
  gemm2_kernel<<<NTILES, 256, 0, stream>>>(h1buf, Wt2, b2, off_al, order, out);
}

// Round 3
// 194.802 us; speedup vs baseline: 1.6010x; 1.6010x over previous
//
#include <hip/hip_runtime.h>
#include <hip/hip_bf16.h>
#include <cstdint>
#include <cstddef>

// Problem constants
#define B_N 8192
#define D_K 1024
#define H_N 400
#define HP  416          // H padded to multiple of 32 (gemm2 K-loop)
#define K2_N 512
#define E_N 16
#define L_N 256
#define TM 64
#define PAD_ROWS (B_N + E_N * TM)   // 9216
#define NTILES (PAD_ROWS / TM)      // 144

typedef short bf16x8 __attribute__((ext_vector_type(8)));
typedef float f32x4 __attribute__((ext_vector_type(4)));

static __device__ __forceinline__ unsigned short f2bf(float f) {
  union { float f; unsigned int u; } c; c.f = f;
  unsigned int u = c.u + 0x7fffu + ((c.u >> 16) & 1u);  // RNE
  return (unsigned short)(u >> 16);
}
static __device__ __forceinline__ unsigned int pkbf(float a, float b) {
  union { __hip_bfloat162 v; unsigned int u; } c;
  c.v = __float22bfloat162_rn(make_float2(a, b));
  return c.u;
}

// ---------------- grouping: hist -> offsets -> scatter ----------------
__global__ __launch_bounds__(256) void hist_kernel(const int* __restrict__ idx,
                                                   int* __restrict__ hist) {
  __shared__ int h[E_N];
  int t = threadIdx.x;
  if (t < E_N) h[t] = 0;
  __syncthreads();
  int b = blockIdx.x * 256 + t;
  atomicAdd(&h[idx[b]], 1);
  __syncthreads();
  if (t < E_N) hist[blockIdx.x * E_N + t] = h[t];
}

__global__ __launch_bounds__(256) void offs_kernel(const int* __restrict__ hist,
                                                   int* __restrict__ off_al,
                                                   int* __restrict__ cur,
                                                   int* __restrict__ order) {
  __shared__ int cnt[E_N];
  int t = threadIdx.x;
  if (t < E_N) {
    int s = 0;
    for (int b = 0; b < 32; ++b) s += hist[b * E_N + t];
    cnt[t] = s;
  }
  __syncthreads();
  if (t == 0) {
    int acc = 0;
    for (int e = 0; e < E_N; ++e) {
      off_al[e] = acc;
      cur[e] = acc;
      acc += ((cnt[e] + TM - 1) / TM) * TM;
    }
    off_al[E_N] = acc;
  }
  for (int i = t; i < PAD_ROWS; i += 256) order[i] = -1;
}

__global__ __launch_bounds__(256) void scatter_kernel(const int* __restrict__ idx,
                                                      int* __restrict__ cur,
                                                      int* __restrict__ order) {
  int b = blockIdx.x * 256 + threadIdx.x;
  int e = idx[b];
  int p = atomicAdd(&cur[e], 1);
  order[p] = b;
}

// ---------------- prep: transpose + cvt W [K][N] f32 -> [N][Kd] bf16 ----------------
__global__ __launch_bounds__(256) void transpose_kernel(const float* __restrict__ src,
                                                        unsigned short* __restrict__ dst,
                                                        int K, int N, int Kd) {
  __shared__ unsigned short Ls[64][72];
  const int e  = blockIdx.z;
  const int k0 = blockIdx.x * 64;
  const int n0 = blockIdx.y * 64;
  const float* S = src + (size_t)e * K * N;
  unsigned short* Dt = dst + (size_t)e * N * Kd;
  const int t = threadIdx.x;
  const int kk = t >> 4;
  const int nn = (t & 15) * 4;
#pragma unroll
  for (int p = 0; p < 4; ++p) {
    int k = k0 + p * 16 + kk;
    int n = n0 + nn;
    float4 v = make_float4(0.f, 0.f, 0.f, 0.f);
    if (k < K && n + 3 < N) v = *(const float4*)(S + (size_t)k * N + n);
    Ls[nn + 0][p * 16 + kk] = f2bf(v.x);
    Ls[nn + 1][p * 16 + kk] = f2bf(v.y);
    Ls[nn + 2][p * 16 + kk] = f2bf(v.z);
    Ls[nn + 3][p * 16 + kk] = f2bf(v.w);
  }
  __syncthreads();
  const int n2 = t >> 3;
  const int ch = t & 7;
#pragma unroll
  for (int p = 0; p < 2; ++p) {
    int n = n0 + p * 32 + n2;
    int k = k0 + ch * 8;
    if (n < N && k < Kd)
      *(uint4*)(Dt + (size_t)n * Kd + k) = *(const uint4*)&Ls[p * 32 + n2][ch * 8];
  }
}

// ---------------- GEMM1: h1 = relu(Xg @ W1[e] + b1[e]) ----------------
// grid (144, 4). n-chunks over 26 n-tiles: start {0,7,14,20}, cnt {7,7,6,6}.
// 4 waves; wave w: 4 m-subtiles x tiles {w, w+4}.
__global__ __launch_bounds__(256) void gemm1_kernel(const float* __restrict__ x,
                                                    const unsigned short* __restrict__ Wt1,
                                                    const float* __restrict__ b1,
                                                    const int* __restrict__ off_al,
                                                    const int* __restrict__ order,
                                                    unsigned short* __restrict__ h1buf) {
  __shared__ int offs[E_N + 1];
  __shared__ int rowidx[TM];
  __shared__ unsigned short As[64 * 40];
  __shared__ unsigned short Bs[112 * 40];
  const int tid = threadIdx.x;
  const int m0 = blockIdx.x * TM;
  const int nb = blockIdx.y;
  const int tstart = (nb < 2) ? 7 * nb : 14 + 6 * (nb - 2);
  const int tcnt   = (nb < 2) ? 7 : 6;
  const int nbase  = tstart * 16;
  if (tid <= E_N) offs[tid] = off_al[tid];
  if (tid < TM) rowidx[tid] = order[m0 + tid];
  __syncthreads();
  const int total = offs[E_N];
  if (m0 >= total) return;
  int e = 0;
  while (m0 >= offs[e + 1]) ++e;

  const int arow = tid >> 2;
  const int akq  = (tid & 3) * 8;
  const long asrc = rowidx[arow];
  const unsigned short* Wt1e = Wt1 + (size_t)e * H_N * D_K;

  const int lane = tid & 63, w = tid >> 6;
  const int ln = lane & 15, q = lane >> 4;
  const int nload = tcnt * 64;  // uint4 count = tcnt*16 rows * 4

  // B row/chunk for each of 2 staging slots
  const int i0 = tid, i1 = tid + 256;
  const int br0 = i0 >> 2, bc0 = (i0 & 3) * 8;
  const int br1 = i1 >> 2, bc1 = (i1 & 3) * 8;
  const int bg0 = nbase + br0, bg1 = nbase + br1;
  const bool v1 = (i1 < nload) && (bg1 < H_N);
  const bool v0 = (bg0 < H_N);   // i0 always < nload

  f32x4 acc[4][2] = {};

  // prefetch k=0
  float4 aA = make_float4(0, 0, 0, 0), aB = aA;
  if (asrc >= 0) {
    aA = *(const float4*)(x + (size_t)asrc * D_K + akq);
    aB = *(const float4*)(x + (size_t)asrc * D_K + akq + 4);
  }
  uint4 breg0 = make_uint4(0, 0, 0, 0), breg1 = breg0;
  if (v0) breg0 = *(const uint4*)(Wt1e + (size_t)bg0 * D_K + bc0);
  if (v1) breg1 = *(const uint4*)(Wt1e + (size_t)bg1 * D_K + bc1);

  for (int k0 = 0; k0 < D_K; k0 += 32) {
    uint4 aw;
    aw.x = pkbf(aA.x, aA.y); aw.y = pkbf(aA.z, aA.w);
    aw.z = pkbf(aB.x, aB.y); aw.w = pkbf(aB.z, aB.w);
    *(uint4*)&As[arow * 40 + akq] = aw;
    *(uint4*)&Bs[br0 * 40 + bc0] = breg0;
    if (i1 < nload) *(uint4*)&Bs[br1 * 40 + bc1] = breg1;
    __syncthreads();

    int kn = k0 + 32;
    if (kn < D_K) {
      if (asrc >= 0) {
        aA = *(const float4*)(x + (size_t)asrc * D_K + kn + akq);
        aB = *(const float4*)(x + (size_t)asrc * D_K + kn + akq + 4);
      }
      if (v0) breg0 = *(const uint4*)(Wt1e + (size_t)bg0 * D_K + kn + bc0);
      if (v1) breg1 = *(const uint4*)(Wt1e + (size_t)bg1 * D_K + kn + bc1);
    }

    bf16x8 af[4];
#pragma unroll
    for (int i = 0; i < 4; ++i)
      af[i] = *(const bf16x8*)&As[(16 * i + ln) * 40 + 8 * q];
#pragma unroll
    for (int t = 0; t < 2; ++t) {
      int tl = w + 4 * t;
      if (tl < tcnt) {
        bf16x8 bfrag = *(const bf16x8*)&Bs[(16 * tl + ln) * 40 + 8 * q];
#pragma unroll
        for (int i = 0; i < 4; ++i)
          acc[i][t] = __builtin_amdgcn_mfma_f32_16x16x32_bf16(af[i], bfrag, acc[i][t], 0, 0, 0);
      }
    }
    __syncthreads();
  }

#pragma unroll
  for (int t = 0; t < 2; ++t) {
    int tl = w + 4 * t;
    if (tl < tcnt) {
      int n = nbase + 16 * tl + ln;
      if (n < H_N) {
        float bias = b1[e * H_N + n];
#pragma unroll
        for (int i = 0; i < 4; ++i) {
#pragma unroll
          for (int r = 0; r < 4; ++r) {
            int m = m0 + 16 * i + 4 * q + r;
            float v = acc[i][t][r] + bias;
            h1buf[(size_t)m * HP + n] = f2bf(fmaxf(v, 0.f));
          }
        }
      }
    }
  }
  // zero K-pad cols [400,416) once per m-tile (chunk 3 owns it)
  if (nb == 3 && tid < TM) {
    uint4 z = make_uint4(0, 0, 0, 0);
    *(uint4*)&h1buf[(size_t)(m0 + tid) * HP + 400] = z;
    *(uint4*)&h1buf[(size_t)(m0 + tid) * HP + 408] = z;
  }
}

// ---------------- GEMM2: out = h1 @ W2[e] + b2[e], scatter ----------------
// grid (144, 4). BN=128 (8 tiles). Wave w: 4 m-subtiles x tiles {w, w+4}.
__global__ __launch_bounds__(256) void gemm2_kernel(const unsigned short* __restrict__ h1buf,
                                                    const unsigned short* __restrict__ Wt2,
                                                    const float* __restrict__ b2,
                                                    const int* __restrict__ off_al,
                                                    const int* __restrict__ order,
                                                    float* __restrict__ out) {
  __shared__ int offs[E_N + 1];
  __shared__ int rowidx[TM];
  __shared__ unsigned short As[64 * 40];
  __shared__ unsigned short Bs[128 * 40];
  const int tid = threadIdx.x;
  const int m0 = blockIdx.x * TM;
  const int nb = blockIdx.y;
  const int nbase = nb * 128;
  if (tid <= E_N) offs[tid] = off_al[tid];
  if (tid < TM) rowidx[tid] = order[m0 + tid];
  __syncthreads();
  const int total = offs[E_N];
  if (m0 >= total) return;
  int e = 0;
  while (m0 >= offs[e + 1]) ++e;

  const int arow = tid >> 2, ach = (tid & 3) * 8;
  const unsigned short* Wt2e = Wt2 + (size_t)e * K2_N * HP;

  const int lane = tid & 63, w = tid >> 6;
  const int ln = lane & 15, q = lane >> 4;

  const int i0 = tid, i1 = tid + 256;
  const int br0 = i0 >> 2, bc0 = (i0 & 3) * 8;
  const int br1 = i1 >> 2, bc1 = (i1 & 3) * 8;

  f32x4 acc[4][2] = {};

  uint4 areg = *(const uint4*)(h1buf + (size_t)(m0 + arow) * HP + ach);
  uint4 breg0 = *(const uint4*)(Wt2e + (size_t)(nbase + br0) * HP + bc0);
  uint4 breg1 = *(const uint4*)(Wt2e + (size_t)(nbase + br1) * HP + bc1);

  for (int k0 = 0; k0 < HP; k0 += 32) {
    *(uint4*)&As[arow * 40 + ach] = areg;
    *(uint4*)&Bs[br0 * 40 + bc0] = breg0;
    *(uint4*)&Bs[br1 * 40 + bc1] = breg1;
    __syncthreads();

    int kn = k0 + 32;
    if (kn < HP) {
      areg  = *(const uint4*)(h1buf + (size_t)(m0 + arow) * HP + kn + ach);
      breg0 = *(const uint4*)(Wt2e + (size_t)(nbase + br0) * HP + kn + bc0);
      breg1 = *(const uint4*)(Wt2e + (size_t)(nbase + br1) * HP + kn + bc1);
    }

    bf16x8 af[4];
#pragma unroll
    for (int i = 0; i < 4; ++i)
      af[i] = *(const bf16x8*)&As[(16 * i + ln) * 40 + 8 * q];
#pragma unroll
    for (int t = 0; t < 2; ++t) {
      int tl = w + 4 * t;
      bf16x8 bfrag = *(const bf16x8*)&Bs[(16 * tl + ln) * 40 + 8 * q];
#pragma unroll
      for (int i = 0; i < 4; ++i)
        acc[i][t] = __builtin_amdgcn_mfma_f32_16x16x32_bf16(af[i], bfrag, acc[i][t], 0, 0, 0);
    }
    __syncthreads();
  }

#pragma unroll
  for (int t = 0; t < 2; ++t) {
    int tl = w + 4 * t;
    int n = nbase + 16 * tl + ln;
    float bias = b2[e * K2_N + n];
#pragma unroll
    for (int i = 0; i < 4; ++i) {
#pragma unroll
      for (int r = 0; r < 4; ++r) {
        int s = rowidx[16 * i + 4 * q + r];
        if (s >= 0) {
          float v = acc[i][t][r] + bias;
          if (n < L_N) out[(size_t)s * L_N + n] = v;
          else         out[(size_t)(B_N + s) * L_N + (n - L_N)] = v;
        }
      }
    }
  }
}

extern "C" void kernel_launch(void* const* d_in, const int* in_sizes, int n_in,
                              void* d_out, int out_size, void* d_ws, size_t ws_size,
                              hipStream_t stream) {
  const float* x   = (const float*)d_in[0];
  const int*   idx = (const int*)d_in[1];
  const float* W1  = (const float*)d_in[2];
  const float* b1  = (const float*)d_in[3];
  const float* W2  = (const float*)d_in[4];
  const float* b2  = (const float*)d_in[5];
  float* out = (float*)d_out;

  // ws layout (bytes) — total requirement 20,814,016 (same as R2's proven floor):
  // off_al@0 | cur@128 | hist@192 | order@2240 | h1buf@39104 (7,667,712)
  // Wt@7,706,816: Wt1 [E][400][1024] bf16 (13,107,200); Wt2 [E][512][416] bf16
  // overlaps the same region (transposed after gemm1 completes).
  char* ws = (char*)d_ws;
  int* off_al = (int*)(ws + 0);
  int* cur    = (int*)(ws + 128);
  int* hist   = (int*)(ws + 192);
  int* order  = (int*)(ws + 2240);
  unsigned short* h1buf = (unsigned short*)(ws + 39104);
  unsigned short* Wt1   = (unsigned short*)(ws + 7706816);
  unsigned short* Wt2   = Wt1;

  hist_kernel<<<32, 256, 0, stream>>>(idx, hist);
  offs_kernel<<<1, 256, 0, stream>>>(hist, off_al, cur, order);
  scatter_kernel<<<32, 256, 0, stream>>>(idx, cur, order);
  transpose_kernel<<<dim3(D_K / 64, 7, E_N), 256, 0, stream>>>(W1, Wt1, D_K, H_N, D_K);
  gemm1_kernel<<<dim3(NTILES, 4), 256, 0, stream>>>(x, Wt1, b1, off_al, order, h1buf);
  transpose_kernel<<<dim3(HP / 64 + 1, K2_N / 64, E_N), 256, 0, stream>>>(W2, Wt2, H_N, K2_N, HP);
  gemm2_kernel<<<dim3(NTILES, 4), 256, 0, stream>>>(h1buf, Wt2, b2, off_al, order, out);
}

// Round 4
// 179.335 us; speedup vs baseline: 1.7391x; 1.0862x over previous
//
#include <hip/hip_runtime.h>
#include <hip/hip_bf16.h>
#include <cstdint>
#include <cstddef>

// Problem constants
#define B_N 8192
#define D_K 1024
#define H_N 400
#define HP  416          // H padded to multiple of 32
#define K2_N 512
#define E_N 16
#define L_N 256
#define TM 64
#define PAD_ROWS (B_N + E_N * TM)   // 9216
#define NTILES (PAD_ROWS / TM)      // 144

typedef short bf16x8 __attribute__((ext_vector_type(8)));
typedef float f32x4 __attribute__((ext_vector_type(4)));

// async global->LDS, 16B per lane; LDS dest = wave-uniform base + lane*16
#define GLDS(gp, lp) __builtin_amdgcn_global_load_lds( \
    (const __attribute__((address_space(1))) unsigned int*)(gp), \
    (__attribute__((address_space(3))) unsigned int*)(lp), 16, 0, 0)

static __device__ __forceinline__ unsigned short f2bf(float f) {
  union { float f; unsigned int u; } c; c.f = f;
  unsigned int u = c.u + 0x7fffu + ((c.u >> 16) & 1u);  // RNE
  return (unsigned short)(u >> 16);
}
static __device__ __forceinline__ unsigned int pkbf(float a, float b) {
  union { __hip_bfloat162 v; unsigned int u; } c;
  c.v = __float22bfloat162_rn(make_float2(a, b));
  return c.u;
}

// ---------------- prep: W-transposes (blocks 0..2687) + grouping (block 2688) ----
// W transpose: [K][N] f32 -> [N pad Nd][K pad Kd] bf16, zero-filled pads.
__global__ __launch_bounds__(256) void prep_kernel(const float* __restrict__ W1,
                                                   const float* __restrict__ W2,
                                                   const int* __restrict__ idx,
                                                   unsigned short* __restrict__ Wt1,
                                                   unsigned short* __restrict__ Wt2,
                                                   int* __restrict__ off_al,
                                                   int* __restrict__ order) {
  const int bid = blockIdx.x;
  const int t = threadIdx.x;
  if (bid < 2688) {
    __shared__ unsigned short Ls[64][72];
    const float* S; unsigned short* Dt; int K, N, Kd, Nd, k0, n0;
    if (bid < 1792) {                    // W1: 16 k-blocks x 7 n-blocks x 16 e
      int e = bid / 112, r = bid % 112;
      k0 = (r % 16) * 64; n0 = (r / 16) * 64;
      S = W1 + (size_t)e * D_K * H_N; Dt = Wt1 + (size_t)e * HP * D_K;
      K = D_K; N = H_N; Kd = D_K; Nd = HP;
    } else {                             // W2: 7 k-blocks x 8 n-blocks x 16 e
      int t2 = bid - 1792; int e = t2 / 56, r = t2 % 56;
      k0 = (r % 7) * 64; n0 = (r / 7) * 64;
      S = W2 + (size_t)e * H_N * K2_N; Dt = Wt2 + (size_t)e * K2_N * HP;
      K = H_N; N = K2_N; Kd = HP; Nd = K2_N;
    }
    const int kk = t >> 4;
    const int nn = (t & 15) * 4;
#pragma unroll
    for (int p = 0; p < 4; ++p) {
      int k = k0 + p * 16 + kk;
      int n = n0 + nn;
      float4 v = make_float4(0.f, 0.f, 0.f, 0.f);
      if (k < K && n + 3 < N) v = *(const float4*)(S + (size_t)k * N + n);
      Ls[nn + 0][p * 16 + kk] = f2bf(v.x);
      Ls[nn + 1][p * 16 + kk] = f2bf(v.y);
      Ls[nn + 2][p * 16 + kk] = f2bf(v.z);
      Ls[nn + 3][p * 16 + kk] = f2bf(v.w);
    }
    __syncthreads();
    const int n2 = t >> 3;
    const int ch = t & 7;
#pragma unroll
    for (int p = 0; p < 2; ++p) {
      int n = n0 + p * 32 + n2;
      int k = k0 + ch * 8;
      if (n < Nd && k < Kd)
        *(uint4*)(Dt + (size_t)n * Kd + k) = *(const uint4*)&Ls[p * 32 + n2][ch * 8];
    }
  } else {
    // grouping: histogram -> padded offsets -> scatter (single block)
    __shared__ int cnt[E_N];
    __shared__ int curS[E_N];
    if (t < E_N) cnt[t] = 0;
    __syncthreads();
    for (int b = t; b < B_N; b += 256) atomicAdd(&cnt[idx[b]], 1);
    __syncthreads();
    if (t == 0) {
      int acc = 0;
      for (int e = 0; e < E_N; ++e) {
        off_al[e] = acc; curS[e] = acc;
        acc += ((cnt[e] + TM - 1) / TM) * TM;
      }
      off_al[E_N] = acc;
    }
    for (int i = t; i < PAD_ROWS; i += 256) order[i] = -1;
    __syncthreads();
    for (int b = t; b < B_N; b += 256) {
      int e = idx[b];
      order[atomicAdd(&curS[e], 1)] = b;
    }
  }
}

// ---------------- gather + convert x -> xg (permuted, bf16, zero pads) -------
__global__ __launch_bounds__(256) void gather_x_kernel(const float* __restrict__ x,
                                                       const int* __restrict__ order,
                                                       unsigned short* __restrict__ xg) {
  const int w = threadIdx.x >> 6, l = threadIdx.x & 63;
  const int row = blockIdx.x * 4 + w;
  const int src = order[row];
  unsigned short* dst = xg + (size_t)row * D_K;
  if (src < 0) {
#pragma unroll
    for (int i = 0; i < 4; ++i)
      *(uint2*)(dst + i * 256 + l * 4) = make_uint2(0, 0);
  } else {
    const float* s = x + (size_t)src * D_K;
#pragma unroll
    for (int i = 0; i < 4; ++i) {
      float4 v = *(const float4*)(s + i * 256 + l * 4);
      uint2 o; o.x = pkbf(v.x, v.y); o.y = pkbf(v.z, v.w);
      *(uint2*)(dst + i * 256 + l * 4) = o;
    }
  }
}

// ---------------- GEMM1: h1 = relu(xg @ Wt1[e]^T + b1[e]) ----------------
// grid (144,4); n-chunks of 7/7/6/6 16-col tiles. DMA staging, dbuf LDS,
// XOR-swizzled 64B rows (chunk' = chunk ^ ((r ^ r>>2)&3)) -> 2-way reads.
__global__ __launch_bounds__(256) void gemm1_kernel(const unsigned short* __restrict__ xg,
                                                    const unsigned short* __restrict__ Wt1,
                                                    const float* __restrict__ b1,
                                                    const int* __restrict__ off_al,
                                                    unsigned short* __restrict__ h1buf) {
  __shared__ unsigned short As[2][64 * 32];
  __shared__ unsigned short Bs[2][112 * 32];
  __shared__ int offs[E_N + 1];
  const int tid = threadIdx.x;
  const int m0 = blockIdx.x * TM;
  const int nb = blockIdx.y;
  const int tstart = (nb < 2) ? 7 * nb : 14 + 6 * (nb - 2);
  const int tcnt   = (nb < 2) ? 7 : 6;
  if (tid <= E_N) offs[tid] = off_al[tid];
  __syncthreads();
  if (m0 >= offs[E_N]) return;
  int e = 0;
  while (m0 >= offs[e + 1]) ++e;
  const unsigned short* Wt1e = Wt1 + (size_t)e * HP * D_K;

  // DMA lane mapping: 16 rows/issue, lane l -> row base+l/4, global chunk (l&3)^s(row)
  const int l = tid & 63, w = tid >> 6;
  const int r4 = l >> 2;
  const int sg = (r4 ^ (r4 >> 2)) & 3;
  const int g8 = ((l & 3) ^ sg) * 8;
  const int tl1 = w + 4;
  const unsigned short* gA  = xg + (size_t)(m0 + 16 * w + r4) * D_K + g8;
  const unsigned short* gB0 = Wt1e + (size_t)((tstart + w) * 16 + r4) * D_K + g8;
  const unsigned short* gB1 = Wt1e + (size_t)((tstart + tl1) * 16 + r4) * D_K + g8;

  // fragment read params
  const int ln = l & 15, q = l >> 4;
  const int sr = (ln ^ (ln >> 2)) & 3;
  const int cq = (q ^ sr) * 8;

  f32x4 acc[4][2] = {};

  GLDS(gA, &As[0][16 * w * 32]);
  GLDS(gB0, &Bs[0][16 * w * 32]);
  if (tl1 < tcnt) GLDS(gB1, &Bs[0][16 * tl1 * 32]);

  for (int k0 = 0; k0 < D_K; k0 += 32) {
    const int cur = (k0 >> 5) & 1;
    const int nxt = cur ^ 1;
    __syncthreads();               // publishes buf[cur] (drains last iter's DMA)
    if (k0 + 32 < D_K) {           // prefetch next step; flies during compute
      GLDS(gA + k0 + 32, &As[nxt][16 * w * 32]);
      GLDS(gB0 + k0 + 32, &Bs[nxt][16 * w * 32]);
      if (tl1 < tcnt) GLDS(gB1 + k0 + 32, &Bs[nxt][16 * tl1 * 32]);
    }
    bf16x8 af[4];
#pragma unroll
    for (int i = 0; i < 4; ++i)
      af[i] = *(const bf16x8*)&As[cur][(16 * i + ln) * 32 + cq];
    {
      bf16x8 bf0 = *(const bf16x8*)&Bs[cur][(16 * w + ln) * 32 + cq];
#pragma unroll
      for (int i = 0; i < 4; ++i)
        acc[i][0] = __builtin_amdgcn_mfma_f32_16x16x32_bf16(af[i], bf0, acc[i][0], 0, 0, 0);
    }
    if (tl1 < tcnt) {
      bf16x8 bf1 = *(const bf16x8*)&Bs[cur][(16 * tl1 + ln) * 32 + cq];
#pragma unroll
      for (int i = 0; i < 4; ++i)
        acc[i][1] = __builtin_amdgcn_mfma_f32_16x16x32_bf16(af[i], bf1, acc[i][1], 0, 0, 0);
    }
  }

#pragma unroll
  for (int t = 0; t < 2; ++t) {
    const int tl = w + 4 * t;
    if (tl < tcnt) {
      const int n = (tstart + tl) * 16 + ln;
      if (n < H_N) {
        const float bias = b1[e * H_N + n];
#pragma unroll
        for (int i = 0; i < 4; ++i)
#pragma unroll
          for (int r = 0; r < 4; ++r) {
            const int m = m0 + 16 * i + 4 * q + r;
            h1buf[(size_t)m * HP + n] = f2bf(fmaxf(acc[i][t][r] + bias, 0.f));
          }
      }
    }
  }
  if (nb == 3 && tid < TM) {   // zero K-pad cols [400,416)
    uint4 z = make_uint4(0, 0, 0, 0);
    *(uint4*)&h1buf[(size_t)(m0 + tid) * HP + 400] = z;
    *(uint4*)&h1buf[(size_t)(m0 + tid) * HP + 408] = z;
  }
}

// ---------------- GEMM2: out = h1 @ Wt2[e]^T + b2[e], scatter ----------------
__global__ __launch_bounds__(256) void gemm2_kernel(const unsigned short* __restrict__ h1buf,
                                                    const unsigned short* __restrict__ Wt2,
                                                    const float* __restrict__ b2,
                                                    const int* __restrict__ off_al,
                                                    const int* __restrict__ order,
                                                    float* __restrict__ out) {
  __shared__ unsigned short As[2][64 * 32];
  __shared__ unsigned short Bs[2][128 * 32];
  __shared__ int offs[E_N + 1];
  __shared__ int rowidx[TM];
  const int tid = threadIdx.x;
  const int m0 = blockIdx.x * TM;
  const int nbase = blockIdx.y * 128;
  if (tid <= E_N) offs[tid] = off_al[tid];
  if (tid < TM) rowidx[tid] = order[m0 + tid];
  __syncthreads();
  if (m0 >= offs[E_N]) return;
  int e = 0;
  while (m0 >= offs[e + 1]) ++e;
  const unsigned short* Wt2e = Wt2 + (size_t)e * K2_N * HP;

  const int l = tid & 63, w = tid >> 6;
  const int r4 = l >> 2;
  const int sg = (r4 ^ (r4 >> 2)) & 3;
  const int g8 = ((l & 3) ^ sg) * 8;
  const int tl1 = w + 4;
  const unsigned short* gA  = h1buf + (size_t)(m0 + 16 * w + r4) * HP + g8;
  const unsigned short* gB0 = Wt2e + (size_t)(nbase + 16 * w + r4) * HP + g8;
  const unsigned short* gB1 = Wt2e + (size_t)(nbase + 16 * tl1 + r4) * HP + g8;

  const int ln = l & 15, q = l >> 4;
  const int sr = (ln ^ (ln >> 2)) & 3;
  const int cq = (q ^ sr) * 8;

  f32x4 acc[4][2] = {};

  GLDS(gA, &As[0][16 * w * 32]);
  GLDS(gB0, &Bs[0][16 * w * 32]);
  GLDS(gB1, &Bs[0][16 * tl1 * 32]);

  for (int k0 = 0; k0 < HP; k0 += 32) {   // 13 steps
    const int cur = (k0 >> 5) & 1;
    const int nxt = cur ^ 1;
    __syncthreads();
    if (k0 + 32 < HP) {
      GLDS(gA + k0 + 32, &As[nxt][16 * w * 32]);
      GLDS(gB0 + k0 + 32, &Bs[nxt][16 * w * 32]);
      GLDS(gB1 + k0 + 32, &Bs[nxt][16 * tl1 * 32]);
    }
    bf16x8 af[4];
#pragma unroll
    for (int i = 0; i < 4; ++i)
      af[i] = *(const bf16x8*)&As[cur][(16 * i + ln) * 32 + cq];
#pragma unroll
    for (int t = 0; t < 2; ++t) {
      const int tl = w + 4 * t;
      bf16x8 bfr = *(const bf16x8*)&Bs[cur][(16 * tl + ln) * 32 + cq];
#pragma unroll
      for (int i = 0; i < 4; ++i)
        acc[i][t] = __builtin_amdgcn_mfma_f32_16x16x32_bf16(af[i], bfr, acc[i][t], 0, 0, 0);
    }
  }

#pragma unroll
  for (int t = 0; t < 2; ++t) {
    const int tl = w + 4 * t;
    const int n = nbase + 16 * tl + ln;
    const float bias = b2[e * K2_N + n];
#pragma unroll
    for (int i = 0; i < 4; ++i)
#pragma unroll
      for (int r = 0; r < 4; ++r) {
        const int s = rowidx[16 * i + 4 * q + r];
        if (s >= 0) {
          const float v = acc[i][t][r] + bias;
          if (n < L_N) out[(size_t)s * L_N + n] = v;
          else         out[(size_t)(B_N + s) * L_N + (n - L_N)] = v;
        }
      }
  }
}

extern "C" void kernel_launch(void* const* d_in, const int* in_sizes, int n_in,
                              void* d_out, int out_size, void* d_ws, size_t ws_size,
                              hipStream_t stream) {
  const float* x   = (const float*)d_in[0];
  const int*   idx = (const int*)d_in[1];
  const float* W1  = (const float*)d_in[2];
  const float* b1  = (const float*)d_in[3];
  const float* W2  = (const float*)d_in[4];
  const float* b2  = (const float*)d_in[5];
  float* out = (float*)d_out;

  // ws layout (bytes), total ~47.0 MB (ws_size observed 256 MiB):
  // off_al@0 | order@2240 (36864) | xg@39104 (18,874,368)
  // h1@18,913,472 (7,667,712) | Wt1@26,581,184 (16x416x1024x2 = 13,631,488)
  // Wt2@40,212,672 (16x512x416x2 = 6,815,744) -> end 47,028,416
  char* ws = (char*)d_ws;
  int* off_al = (int*)(ws + 0);
  int* order  = (int*)(ws + 2240);
  unsigned short* xg  = (unsigned short*)(ws + 39104);
  unsigned short* h1  = (unsigned short*)(ws + 18913472);
  unsigned short* Wt1 = (unsigned short*)(ws + 26581184);
  unsigned short* Wt2 = (unsigned short*)(ws + 40212672);

  prep_kernel<<<2689, 256, 0, stream>>>(W1, W2, idx, Wt1, Wt2, off_al, order);
  gather_x_kernel<<<PAD_ROWS / 4, 256, 0, stream>>>(x, order, xg);
  gemm1_kernel<<<dim3(NTILES, 4), 256, 0, stream>>>(xg, Wt1, b1, off_al, h1);
  gemm2_kernel<<<dim3(NTILES, 4), 256, 0, stream>>>(h1, Wt2, b2, off_al, order, out);
}

// Round 5
// 175.441 us; speedup vs baseline: 1.7777x; 1.0222x over previous
//
#include <hip/hip_runtime.h>
#include <hip/hip_bf16.h>
#include <cstdint>
#include <cstddef>

// Problem constants
#define B_N 8192
#define D_K 1024
#define H_N 400
#define HP  416          // H padded to multiple of 32
#define K2_N 512
#define E_N 16
#define L_N 256
#define TM 64
#define PAD_ROWS (B_N + E_N * TM)   // 9216
#define NTILES (PAD_ROWS / TM)      // 144

typedef short bf16x8 __attribute__((ext_vector_type(8)));
typedef float f32x4 __attribute__((ext_vector_type(4)));

// async global->LDS, 16B per lane; LDS dest = wave-uniform base + lane*16.
// Global address may be fully per-lane (gather OK).
#define GLDS(gp, lp) __builtin_amdgcn_global_load_lds( \
    (const __attribute__((address_space(1))) unsigned int*)(gp), \
    (__attribute__((address_space(3))) unsigned int*)(lp), 16, 0, 0)

static __device__ __forceinline__ unsigned short f2bf(float f) {
  union { float f; unsigned int u; } c; c.f = f;
  unsigned int u = c.u + 0x7fffu + ((c.u >> 16) & 1u);  // RNE
  return (unsigned short)(u >> 16);
}
static __device__ __forceinline__ unsigned int pkbf(float a, float b) {
  union { __hip_bfloat162 v; unsigned int u; } c;
  c.v = __float22bfloat162_rn(make_float2(a, b));
  return c.u;
}

// ---------------- prep (one launch, independent blocks): ----------------
// blocks [0,1792):   W1 transpose [1024][400] f32 -> [416][1024] bf16 (zero-pad)
// blocks [1792,2688): W2 transpose [400][512] f32 -> [512][416] bf16 (zero-pad)
// blocks [2688,3200): x convert f32 -> bf16 (same layout, 16 rows/block)
// block  3200:        grouping (hist -> padded offsets -> scatter) + zero row
__global__ __launch_bounds__(256) void prep_kernel(const float* __restrict__ W1,
                                                   const float* __restrict__ W2,
                                                   const float* __restrict__ x,
                                                   const int* __restrict__ idx,
                                                   unsigned short* __restrict__ Wt1,
                                                   unsigned short* __restrict__ Wt2,
                                                   unsigned short* __restrict__ xc,
                                                   int* __restrict__ off_al,
                                                   int* __restrict__ order) {
  const int bid = blockIdx.x;
  const int t = threadIdx.x;
  if (bid < 2688) {
    __shared__ unsigned short Ls[64][72];
    const float* S; unsigned short* Dt; int K, N, Kd, Nd, k0, n0;
    if (bid < 1792) {                    // W1: 16 k-blocks x 7 n-blocks x 16 e
      int e = bid / 112, r = bid % 112;
      k0 = (r % 16) * 64; n0 = (r / 16) * 64;
      S = W1 + (size_t)e * D_K * H_N; Dt = Wt1 + (size_t)e * HP * D_K;
      K = D_K; N = H_N; Kd = D_K; Nd = HP;
    } else {                             // W2: 7 k-blocks x 8 n-blocks x 16 e
      int t2 = bid - 1792; int e = t2 / 56, r = t2 % 56;
      k0 = (r % 7) * 64; n0 = (r / 7) * 64;
      S = W2 + (size_t)e * H_N * K2_N; Dt = Wt2 + (size_t)e * K2_N * HP;
      K = H_N; N = K2_N; Kd = HP; Nd = K2_N;
    }
    const int kk = t >> 4;
    const int nn = (t & 15) * 4;
#pragma unroll
    for (int p = 0; p < 4; ++p) {
      int k = k0 + p * 16 + kk;
      int n = n0 + nn;
      float4 v = make_float4(0.f, 0.f, 0.f, 0.f);
      if (k < K && n + 3 < N) v = *(const float4*)(S + (size_t)k * N + n);
      Ls[nn + 0][p * 16 + kk] = f2bf(v.x);
      Ls[nn + 1][p * 16 + kk] = f2bf(v.y);
      Ls[nn + 2][p * 16 + kk] = f2bf(v.z);
      Ls[nn + 3][p * 16 + kk] = f2bf(v.w);
    }
    __syncthreads();
    const int n2 = t >> 3;
    const int ch = t & 7;
#pragma unroll
    for (int p = 0; p < 2; ++p) {
      int n = n0 + p * 32 + n2;
      int k = k0 + ch * 8;
      if (n < Nd && k < Kd)
        *(uint4*)(Dt + (size_t)n * Kd + k) = *(const uint4*)&Ls[p * 32 + n2][ch * 8];
    }
  } else if (bid < 3200) {
    // x convert: 16 rows per block, row-coalesced
    const int xb = bid - 2688;
    const float* S = x + (size_t)xb * 16 * D_K;
    unsigned short* Dp = xc + (size_t)xb * 16 * D_K;
#pragma unroll
    for (int i = 0; i < 16; ++i) {
      float4 v = *(const float4*)(S + i * D_K + t * 4);
      uint2 o; o.x = pkbf(v.x, v.y); o.y = pkbf(v.z, v.w);
      *(uint2*)(Dp + i * D_K + t * 4) = o;
    }
  } else {
    // grouping + zero pad-row (xc row B_N)
    __shared__ int cnt[E_N];
    __shared__ int curS[E_N];
    *(uint2*)(xc + (size_t)B_N * D_K + t * 4) = make_uint2(0, 0);
    if (t < E_N) cnt[t] = 0;
    __syncthreads();
    for (int b = t; b < B_N; b += 256) atomicAdd(&cnt[idx[b]], 1);
    __syncthreads();
    if (t == 0) {
      int acc = 0;
      for (int e = 0; e < E_N; ++e) {
        off_al[e] = acc; curS[e] = acc;
        acc += ((cnt[e] + TM - 1) / TM) * TM;
      }
      off_al[E_N] = acc;
    }
    for (int i = t; i < PAD_ROWS; i += 256) order[i] = -1;
    __syncthreads();
    for (int b = t; b < B_N; b += 256) {
      int e = idx[b];
      order[atomicAdd(&curS[e], 1)] = b;
    }
  }
}

// ---------------- GEMM1: h1 = relu(gather(xc) @ Wt1[e]^T + b1[e]) ----------------
// grid (144,4); n-chunks of 7/7/6/6 16-col tiles. A rows DMA-gathered via order
// (pad -> zero row B_N). Dbuf LDS, XOR-swizzled 64B rows -> 2-way LDS reads.
__global__ __launch_bounds__(256) void gemm1_kernel(const unsigned short* __restrict__ xc,
                                                    const unsigned short* __restrict__ Wt1,
                                                    const float* __restrict__ b1,
                                                    const int* __restrict__ off_al,
                                                    const int* __restrict__ order,
                                                    unsigned short* __restrict__ h1buf) {
  __shared__ unsigned short As[2][64 * 32];
  __shared__ unsigned short Bs[2][112 * 32];
  __shared__ int offs[E_N + 1];
  __shared__ int rowidx[TM];
  const int tid = threadIdx.x;
  const int m0 = blockIdx.x * TM;
  const int nb = blockIdx.y;
  const int tstart = (nb < 2) ? 7 * nb : 14 + 6 * (nb - 2);
  const int tcnt   = (nb < 2) ? 7 : 6;
  if (tid <= E_N) offs[tid] = off_al[tid];
  if (tid < TM) {
    int s = order[m0 + tid];
    rowidx[tid] = (s < 0) ? B_N : s;   // pad -> zero row
  }
  __syncthreads();
  if (m0 >= offs[E_N]) return;
  int e = 0;
  while (m0 >= offs[e + 1]) ++e;
  const unsigned short* Wt1e = Wt1 + (size_t)e * HP * D_K;

  const int l = tid & 63, w = tid >> 6;
  const int r4 = l >> 2;
  const int sg = (r4 ^ (r4 >> 2)) & 3;
  const int g8 = ((l & 3) ^ sg) * 8;
  const int tl1 = w + 4;
  const unsigned short* gA  = xc + (size_t)rowidx[16 * w + r4] * D_K + g8;
  const unsigned short* gB0 = Wt1e + (size_t)((tstart + w) * 16 + r4) * D_K + g8;
  const unsigned short* gB1 = Wt1e + (size_t)((tstart + tl1) * 16 + r4) * D_K + g8;

  const int ln = l & 15, q = l >> 4;
  const int sr = (ln ^ (ln >> 2)) & 3;
  const int cq = (q ^ sr) * 8;

  f32x4 acc[4][2] = {};

  GLDS(gA, &As[0][16 * w * 32]);
  GLDS(gB0, &Bs[0][16 * w * 32]);
  if (tl1 < tcnt) GLDS(gB1, &Bs[0][16 * tl1 * 32]);

  for (int k0 = 0; k0 < D_K; k0 += 32) {
    const int cur = (k0 >> 5) & 1;
    const int nxt = cur ^ 1;
    __syncthreads();               // publishes buf[cur]
    if (k0 + 32 < D_K) {           // prefetch next; flies during compute
      GLDS(gA + k0 + 32, &As[nxt][16 * w * 32]);
      GLDS(gB0 + k0 + 32, &Bs[nxt][16 * w * 32]);
      if (tl1 < tcnt) GLDS(gB1 + k0 + 32, &Bs[nxt][16 * tl1 * 32]);
    }
    bf16x8 af[4];
#pragma unroll
    for (int i = 0; i < 4; ++i)
      af[i] = *(const bf16x8*)&As[cur][(16 * i + ln) * 32 + cq];
    {
      bf16x8 bf0 = *(const bf16x8*)&Bs[cur][(16 * w + ln) * 32 + cq];
#pragma unroll
      for (int i = 0; i < 4; ++i)
        acc[i][0] = __builtin_amdgcn_mfma_f32_16x16x32_bf16(af[i], bf0, acc[i][0], 0, 0, 0);
    }
    if (tl1 < tcnt) {
      bf16x8 bf1 = *(const bf16x8*)&Bs[cur][(16 * tl1 + ln) * 32 + cq];
#pragma unroll
      for (int i = 0; i < 4; ++i)
        acc[i][1] = __builtin_amdgcn_mfma_f32_16x16x32_bf16(af[i], bf1, acc[i][1], 0, 0, 0);
    }
  }

#pragma unroll
  for (int t = 0; t < 2; ++t) {
    const int tl = w + 4 * t;
    if (tl < tcnt) {
      const int n = (tstart + tl) * 16 + ln;
      if (n < H_N) {
        const float bias = b1[e * H_N + n];
#pragma unroll
        for (int i = 0; i < 4; ++i)
#pragma unroll
          for (int r = 0; r < 4; ++r) {
            const int m = m0 + 16 * i + 4 * q + r;
            h1buf[(size_t)m * HP + n] = f2bf(fmaxf(acc[i][t][r] + bias, 0.f));
          }
      }
    }
  }
  if (nb == 3 && tid < TM) {   // zero K-pad cols [400,416)
    uint4 z = make_uint4(0, 0, 0, 0);
    *(uint4*)&h1buf[(size_t)(m0 + tid) * HP + 400] = z;
    *(uint4*)&h1buf[(size_t)(m0 + tid) * HP + 408] = z;
  }
}

// ---------------- GEMM2: out = h1 @ Wt2[e]^T + b2[e], scatter ----------------
__global__ __launch_bounds__(256) void gemm2_kernel(const unsigned short* __restrict__ h1buf,
                                                    const unsigned short* __restrict__ Wt2,
                                                    const float* __restrict__ b2,
                                                    const int* __restrict__ off_al,
                                                    const int* __restrict__ order,
                                                    float* __restrict__ out) {
  __shared__ unsigned short As[2][64 * 32];
  __shared__ unsigned short Bs[2][128 * 32];
  __shared__ int offs[E_N + 1];
  __shared__ int rowidx[TM];
  const int tid = threadIdx.x;
  const int m0 = blockIdx.x * TM;
  const int nbase = blockIdx.y * 128;
  if (tid <= E_N) offs[tid] = off_al[tid];
  if (tid < TM) rowidx[tid] = order[m0 + tid];
  __syncthreads();
  if (m0 >= offs[E_N]) return;
  int e = 0;
  while (m0 >= offs[e + 1]) ++e;
  const unsigned short* Wt2e = Wt2 + (size_t)e * K2_N * HP;

  const int l = tid & 63, w = tid >> 6;
  const int r4 = l >> 2;
  const int sg = (r4 ^ (r4 >> 2)) & 3;
  const int g8 = ((l & 3) ^ sg) * 8;
  const int tl1 = w + 4;
  const unsigned short* gA  = h1buf + (size_t)(m0 + 16 * w + r4) * HP + g8;
  const unsigned short* gB0 = Wt2e + (size_t)(nbase + 16 * w + r4) * HP + g8;
  const unsigned short* gB1 = Wt2e + (size_t)(nbase + 16 * tl1 + r4) * HP + g8;

  const int ln = l & 15, q = l >> 4;
  const int sr = (ln ^ (ln >> 2)) & 3;
  const int cq = (q ^ sr) * 8;

  f32x4 acc[4][2] = {};

  GLDS(gA, &As[0][16 * w * 32]);
  GLDS(gB0, &Bs[0][16 * w * 32]);
  GLDS(gB1, &Bs[0][16 * tl1 * 32]);

  for (int k0 = 0; k0 < HP; k0 += 32) {   // 13 steps
    const int cur = (k0 >> 5) & 1;
    const int nxt = cur ^ 1;
    __syncthreads();
    if (k0 + 32 < HP) {
      GLDS(gA + k0 + 32, &As[nxt][16 * w * 32]);
      GLDS(gB0 + k0 + 32, &Bs[nxt][16 * w * 32]);
      GLDS(gB1 + k0 + 32, &Bs[nxt][16 * tl1 * 32]);
    }
    bf16x8 af[4];
#pragma unroll
    for (int i = 0; i < 4; ++i)
      af[i] = *(const bf16x8*)&As[cur][(16 * i + ln) * 32 + cq];
#pragma unroll
    for (int t = 0; t < 2; ++t) {
      const int tl = w + 4 * t;
      bf16x8 bfr = *(const bf16x8*)&Bs[cur][(16 * tl + ln) * 32 + cq];
#pragma unroll
      for (int i = 0; i < 4; ++i)
        acc[i][t] = __builtin_amdgcn_mfma_f32_16x16x32_bf16(af[i], bfr, acc[i][t], 0, 0, 0);
    }
  }

#pragma unroll
  for (int t = 0; t < 2; ++t) {
    const int tl = w + 4 * t;
    const int n = nbase + 16 * tl + ln;
    const float bias = b2[e * K2_N + n];
#pragma unroll
    for (int i = 0; i < 4; ++i)
#pragma unroll
      for (int r = 0; r < 4; ++r) {
        const int s = rowidx[16 * i + 4 * q + r];
        if (s >= 0) {
          const float v = acc[i][t][r] + bias;
          if (n < L_N) out[(size_t)s * L_N + n] = v;
          else         out[(size_t)(B_N + s) * L_N + (n - L_N)] = v;
        }
      }
  }
}

extern "C" void kernel_launch(void* const* d_in, const int* in_sizes, int n_in,
                              void* d_out, int out_size, void* d_ws, size_t ws_size,
                              hipStream_t stream) {
  const float* x   = (const float*)d_in[0];
  const int*   idx = (const int*)d_in[1];
  const float* W1  = (const float*)d_in[2];
  const float* b1  = (const float*)d_in[3];
  const float* W2  = (const float*)d_in[4];
  const float* b2  = (const float*)d_in[5];
  float* out = (float*)d_out;

  // ws layout (bytes), total ~44.9 MB:
  // off_al@0 | order@2240 (36864) | xc@39104 ((8192+1)x1024x2 = 16,779,264)
  // h1@16,818,368 (9216x416x2 = 7,667,712) | Wt1@24,486,080 (16x416x1024x2)
  // Wt2@38,117,568 (16x512x416x2 = 6,815,744) -> end 44,933,312
  char* ws = (char*)d_ws;
  int* off_al = (int*)(ws + 0);
  int* order  = (int*)(ws + 2240);
  unsigned short* xc  = (unsigned short*)(ws + 39104);
  unsigned short* h1  = (unsigned short*)(ws + 16818368);
  unsigned short* Wt1 = (unsigned short*)(ws + 24486080);
  unsigned short* Wt2 = (unsigned short*)(ws + 38117568);

  prep_kernel<<<3201, 256, 0, stream>>>(W1, W2, x, idx, Wt1, Wt2, xc, off_al, order);
  gemm1_kernel<<<dim3(NTILES, 4), 256, 0, stream>>>(xc, Wt1, b1, off_al, order, h1);
  gemm2_kernel<<<dim3(NTILES, 4), 256, 0, stream>>>(h1, Wt2, b2, off_al, order, out);
}